// Round 24
// baseline (598.041 us; speedup 1.0000x reference)
//
#include <hip/hip_runtime.h>
#include <hip/hip_bf16.h>
#include <math.h>

// ---------- constants (fixed problem shape) ----------
#define BATCH 8
#define CCH 192
#define LTOK 16384            // 128*128
#define BL 131072LL           // BATCH * LTOK
#define NWIN 2048             // BATCH * 16 * 16
#define NHEADS 6

typedef __hip_bfloat16 bf16;
typedef __bf16 bfr;  // raw bf16 for MFMA fragments
typedef bfr bf16x8 __attribute__((ext_vector_type(8)));
typedef float f32x4 __attribute__((ext_vector_type(4)));
typedef unsigned short u16x8 __attribute__((ext_vector_type(8)));
typedef unsigned short u16x4 __attribute__((ext_vector_type(4)));
typedef unsigned int u32x2 __attribute__((ext_vector_type(2)));

// ---------- dtype flags (1 = f32, 0 = bf16), probed at runtime ----------
#define FX     0
#define FN1W   1
#define FN1B   2
#define FQKVW  3
#define FPROJW 4
#define FPROJB 5
#define FBIAS  6
#define FCONVW 7
#define FCG1   8
#define FCG2   9
#define FN2W   10
#define FN2B   11
#define FFC1   12
#define FSMIX  13
#define FFC2   14

struct InPtrs { const void* p[15]; int n[15]; };

__device__ __forceinline__ float ldin(const void* p, long long i, int f32) {
    return f32 ? ((const float*)p)[i]
               : __bfloat162float(((const bf16*)p)[i]);
}

__device__ __forceinline__ float bfcvt(unsigned short u) {
    return __uint_as_float((unsigned)u << 16);
}

// 4 consecutive elements, dtype-flag dispatch (flag is wave-uniform)
__device__ __forceinline__ f32x4 ld4f(const void* p, long long i, int f32) {
    if (f32) return *(const f32x4*)((const float*)p + i);
    u16x4 v = *(const u16x4*)((const bf16*)p + i);
    f32x4 r;
    r[0] = bfcvt(v[0]); r[1] = bfcvt(v[1]); r[2] = bfcvt(v[2]); r[3] = bfcvt(v[3]);
    return r;
}
__device__ __forceinline__ f32x4 ld4b(const bf16* p, long long i) {
    u16x4 v = *(const u16x4*)(p + i);
    f32x4 r;
    r[0] = bfcvt(v[0]); r[1] = bfcvt(v[1]); r[2] = bfcvt(v[2]); r[3] = bfcvt(v[3]);
    return r;
}
__device__ __forceinline__ void st4b(bf16* p, long long i, f32x4 v) {
    union { bf16 h; unsigned short u; } cv;
    u16x4 o;
    cv.h = __float2bfloat16(v[0]); o[0] = cv.u;
    cv.h = __float2bfloat16(v[1]); o[1] = cv.u;
    cv.h = __float2bfloat16(v[2]); o[2] = cv.u;
    cv.h = __float2bfloat16(v[3]); o[3] = cv.u;
    *(u16x4*)(p + i) = o;
}

// pack two f32 -> one u32 of two bf16 (lo = a, hi = b)
__device__ __forceinline__ unsigned pk2bf(float a, float b) {
    union { bf16 h; unsigned short u; } ca, cb;
    ca.h = __float2bfloat16(a);
    cb.h = __float2bfloat16(b);
    return (unsigned)ca.u | ((unsigned)cb.u << 16);
}

__device__ __forceinline__ float gelu_f(float v) {
    return 0.5f * v * (1.0f + erff(v * 0.70710678118654752f));
}

// ---------- local dtype probe (block-level, re-run per consumer block) ----------
__device__ int local_probe(const void* p_, int n) {
    __shared__ int sh0, sh1, sh2;
    if (threadIdx.x == 0) { sh0 = 0; sh1 = 0; sh2 = 0; }
    __syncthreads();
    const bf16* p = (const bf16*)p_;
    int m = n < 2048 ? n : 2048;
    bool insane = false, evennz = false, oddnz = false;
    for (int i = threadIdx.x; i < m; i += 256) {
        float v = __bfloat162float(p[i]);
        if (!(fabsf(v) <= 1e9f)) insane = true;   // NaN/inf/huge
        if (v != 0.0f) { if (i & 1) oddnz = true; else evennz = true; }
    }
    if (insane) sh0 = 1;
    if (evennz) sh1 = 1;
    if (oddnz)  sh2 = 1;
    __syncthreads();
    return (sh0 || (!sh1 && sh2)) ? 1 : 0;
}

// ---------- fused prologue: probe + transposes + pooled zero, one dispatch ----------
__global__ __launch_bounds__(256)
void prep_k(InPtrs ip, int* __restrict__ flags,
            bf16* __restrict__ qkv_wT, bf16* __restrict__ proj_wT,
            bf16* __restrict__ fc1_wT, bf16* __restrict__ fc2_wT,
            float* __restrict__ convwT, float* __restrict__ smixwT,
            float* __restrict__ pooled) {
    int blk = blockIdx.x;
    // section 0: probe -> flags [15 blocks]
    if (blk < 15) {
        int f = local_probe(ip.p[blk], ip.n[blk]);
        if (threadIdx.x == 0) flags[blk] = f;
        return;
    }
    blk -= 15;
    // section 1: qkv_w [192,576] -> qkv_wT [576,192]  [432 blocks]
    if (blk < 432) {
        int f = local_probe(ip.p[FQKVW], ip.n[FQKVW]);
        int idx = blk * 256 + threadIdx.x;
        int k = idx / 576, n = idx - k * 576;
        qkv_wT[(long long)n * 192 + k] = __float2bfloat16(ldin(ip.p[FQKVW], idx, f));
        return;
    }
    blk -= 432;
    // section 2: proj_w [192,192] -> proj_wT [192,192]  [144 blocks]
    if (blk < 144) {
        int f = local_probe(ip.p[FPROJW], ip.n[FPROJW]);
        int idx = blk * 256 + threadIdx.x;
        int k = idx / 192, n = idx - k * 192;
        proj_wT[(long long)n * 192 + k] = __float2bfloat16(ldin(ip.p[FPROJW], idx, f));
        return;
    }
    blk -= 144;
    // section 3: fc1_w [192,384] -> fc1_wT [384,192]  [288 blocks]
    if (blk < 288) {
        int f = local_probe(ip.p[FFC1], ip.n[FFC1]);
        int idx = blk * 256 + threadIdx.x;
        int k = idx / 384, n = idx - k * 384;
        fc1_wT[(long long)n * 192 + k] = __float2bfloat16(ldin(ip.p[FFC1], idx, f));
        return;
    }
    blk -= 288;
    // section 4: fc2_w [384,192] -> fc2_wT [192,384]  [288 blocks]
    if (blk < 288) {
        int f = local_probe(ip.p[FFC2], ip.n[FFC2]);
        int idx = blk * 256 + threadIdx.x;
        int k = idx / 192, n = idx - k * 192;
        fc2_wT[(long long)n * 384 + k] = __float2bfloat16(ldin(ip.p[FFC2], idx, f));
        return;
    }
    blk -= 288;
    // section 5: conv_w [192,1,3,3] -> convwT [9][192]  [7 blocks]
    if (blk < 7) {
        int f = local_probe(ip.p[FCONVW], ip.n[FCONVW]);
        int idx = blk * 256 + threadIdx.x;
        if (idx < 192 * 9) {
            int c = idx / 9, t = idx - c * 9;
            convwT[t * 192 + c] = ldin(ip.p[FCONVW], idx, f);
        }
        return;
    }
    blk -= 7;
    // section 6: smix_w [384,1,3,3] -> smixwT [9][384]  [14 blocks]
    if (blk < 14) {
        int f = local_probe(ip.p[FSMIX], ip.n[FSMIX]);
        int idx = blk * 256 + threadIdx.x;
        if (idx < 384 * 9) {
            int c = idx / 9, t = idx - c * 9;
            smixwT[t * 384 + c] = ldin(ip.p[FSMIX], idx, f);
        }
        return;
    }
    blk -= 14;
    // section 7: zero pooled [6 blocks, 1536 floats]
    {
        int idx = blk * 256 + threadIdx.x;
        if (idx < BATCH * CCH) pooled[idx] = 0.f;
    }
}

// ---------- LayerNorm, 16 lanes per token, vectorized ----------
__global__ __launch_bounds__(256)
void ln_kernel(const void* __restrict__ x, const void* __restrict__ w,
               const void* __restrict__ b, bf16* __restrict__ out,
               const int* flags) {
    int fx = flags[FX], fw = flags[FN1W], fb = flags[FN1B];
    int wv = threadIdx.x >> 6, lane = threadIdx.x & 63;
    int gw = lane >> 4, l16 = lane & 15;
    long long t = (long long)blockIdx.x * 16 + wv * 4 + gw;
    long long base = t * CCH;
    f32x4 v[3];
#pragma unroll
    for (int k = 0; k < 3; ++k)
        v[k] = ld4f(x, base + l16 * 4 + 64 * k, fx);
    float s = 0.f;
#pragma unroll
    for (int k = 0; k < 3; ++k) s += v[k][0] + v[k][1] + v[k][2] + v[k][3];
    s += __shfl_xor(s, 1); s += __shfl_xor(s, 2);
    s += __shfl_xor(s, 4); s += __shfl_xor(s, 8);
    float mean = s * (1.0f / 192.0f);
    float vs = 0.f;
#pragma unroll
    for (int k = 0; k < 3; ++k)
#pragma unroll
        for (int j = 0; j < 4; ++j) {
            float d = v[k][j] - mean;
            vs += d * d;
        }
    vs += __shfl_xor(vs, 1); vs += __shfl_xor(vs, 2);
    vs += __shfl_xor(vs, 4); vs += __shfl_xor(vs, 8);
    float rstd = rsqrtf(vs * (1.0f / 192.0f) + 1e-5f);
#pragma unroll
    for (int k = 0; k < 3; ++k) {
        int c0 = l16 * 4 + 64 * k;
        f32x4 wv4 = ld4f(w, c0, fw);
        f32x4 bv4 = ld4f(b, c0, fb);
        f32x4 o;
#pragma unroll
        for (int j = 0; j < 4; ++j)
            o[j] = (v[k][j] - mean) * rstd * wv4[j] + bv4[j];
        st4b(out, base + c0, o);
    }
}

// ---------- LDS-staged MFMA GEMM (R8-verified single-buffer form) ----------
// EPI=0 (WINM): M-tiles window-aligned; C stores into window/head-major
// qkvw[sel][w][h][tin][32], all writes confined to one window's region.
template<int EPI, int KK, int NN, typename CT>
__global__ __launch_bounds__(256)
void gemm2_k(const bf16* __restrict__ A_, const bf16* __restrict__ BT_,
             CT* __restrict__ Cmat, const void* __restrict__ bias,
             const float* __restrict__ res, const int* __restrict__ flags) {
    constexpr int KT = KK / 192;          // k-tiles of 192
    constexpr int NC = NN / 64;           // n-chunks of 64
    constexpr int NITER = NC * KT;
    constexpr int GSTR = KK * 2;          // global row stride (bytes)
    constexpr bool WINM = (EPI == 0);
    __shared__ __align__(16) char Ts[64 * 384];   // shared A-prologue / B-tile buffer

    const int fb = (EPI == 1) ? flags[FPROJB] : 0;
    const int tid = threadIdx.x;
    const int lane = tid & 63, wv = tid >> 6;
    const int r16 = lane & 15, q = lane >> 4;
    const long long m0 = (long long)blockIdx.x * 64;
    const int swz = (r16 & 7) << 4;

    // window decomposition (WINM only)
    const int wdx = blockIdx.x;
    const int wb = wdx >> 8, wrem = wdx & 255, wy = wrem >> 4, wx = wrem & 15;
    const long long tokbase = (long long)wb * LTOK + (wy * 8) * 128 + wx * 8;

    f32x4 pre[6];
    auto loadB = [&](int itn) {
        int nc2 = itn / KT, kt2 = itn - nc2 * KT;
#pragma unroll
        for (int p = 0; p < 6; ++p) {
            int off = p * 4096 + tid * 16;
            int row = off / 384, col = off - row * 384;
            pre[p] = *(const f32x4*)((const char*)BT_ +
                     (long long)(nc2 * 64 + row) * GSTR + kt2 * 384 + col);
        }
    };
    auto writeT = [&]() {
#pragma unroll
        for (int p = 0; p < 6; ++p) {
            int off = p * 4096 + tid * 16;
            int row = off / 384, col = off - row * 384;
            *(f32x4*)(Ts + row * 384 + (col ^ ((row & 7) << 4))) = pre[p];
        }
    };

    loadB(0);                             // B(0) in flight during A prologue

    // ---- A prologue: per-k-tile stage through Ts, hoist fragments ----
    bf16x8 afrag[KK / 32];
    const char* Arow = Ts + (wv * 16 + r16) * 384;
    const char* asrc = (const char*)A_;
#pragma unroll
    for (int kt = 0; kt < KT; ++kt) {
#pragma unroll
        for (int p = 0; p < 6; ++p) {
            int off = p * 4096 + tid * 16;
            int row = off / 384, col = off - row * 384;
            long long grow = WINM ? (tokbase + (row >> 3) * 128 + (row & 7))
                                  : (m0 + row);
            *(f32x4*)(Ts + row * 384 + (col ^ ((row & 7) << 4))) =
                *(const f32x4*)(asrc + grow * GSTR + kt * 384 + col);
        }
        __syncthreads();
#pragma unroll
        for (int ks = 0; ks < 6; ++ks)
            afrag[kt * 6 + ks] = *(const bf16x8*)(Arow + ((ks * 64 + q * 16) ^ swz));
        __syncthreads();                  // readers done before buffer reuse
    }
    writeT();                             // B(0) -> Ts
    __syncthreads();

    f32x4 acc0, acc1, acc2, acc3;
    float resv[16];

    for (int it = 0; it < NITER; ++it) {
        const int nc = it / KT, kt = it - nc * KT;
        if (kt == 0) {
            acc0 = f32x4{0.f, 0.f, 0.f, 0.f};
            acc1 = acc0; acc2 = acc0; acc3 = acc0;
            if (EPI == 3) {               // prefetch residual ahead of epilogue
#pragma unroll
                for (int j = 0; j < 4; ++j)
#pragma unroll
                    for (int r = 0; r < 4; ++r)
                        resv[j * 4 + r] =
                            res[(m0 + wv * 16 + q * 4 + r) * NN + nc * 64 + j * 16 + r16];
            }
        }
        const bool nxt = (it + 1 < NITER);
        if (nxt) loadB(it + 1);           // issue next B-tile early
#pragma unroll
        for (int ks = 0; ks < 6; ++ks) {
            bf16x8 a = afrag[kt * 6 + ks];
            const char* bb = Ts + r16 * 384 + ((ks * 64 + q * 16) ^ swz);
            bf16x8 b0 = *(const bf16x8*)(bb);
            bf16x8 b1 = *(const bf16x8*)(bb + 16 * 384);
            bf16x8 b2 = *(const bf16x8*)(bb + 32 * 384);
            bf16x8 b3 = *(const bf16x8*)(bb + 48 * 384);
            acc0 = __builtin_amdgcn_mfma_f32_16x16x32_bf16(a, b0, acc0, 0, 0, 0);
            acc1 = __builtin_amdgcn_mfma_f32_16x16x32_bf16(a, b1, acc1, 0, 0, 0);
            acc2 = __builtin_amdgcn_mfma_f32_16x16x32_bf16(a, b2, acc2, 0, 0, 0);
            acc3 = __builtin_amdgcn_mfma_f32_16x16x32_bf16(a, b3, acc3, 0, 0, 0);
        }
        __syncthreads();                  // all waves done reading Ts
        if (nxt) writeT();
        if (kt == KT - 1) {
            f32x4 accs[4] = {acc0, acc1, acc2, acc3};
#pragma unroll
            for (int j = 0; j < 4; ++j) {
                int col = nc * 64 + j * 16 + r16;
#pragma unroll
                for (int r = 0; r < 4; ++r) {
                    float v = accs[j][r];
                    if (EPI == 1) v += ldin(bias, col, fb);
                    if (EPI == 2) v = gelu_f(v);
                    if (EPI == 3) v += resv[j * 4 + r];
                    if (WINM) {
                        int tin = wv * 16 + q * 4 + r;
                        int sel = col / 192, rem2 = col - sel * 192;
                        int hh = rem2 >> 5, d = rem2 & 31;
                        Cmat[((((long long)sel * NWIN + wdx) * 6 + hh) * 64 + tin) * 32 + d] = (CT)v;
                    } else {
                        long long row = m0 + wv * 16 + q * 4 + r;
                        Cmat[row * NN + col] = (CT)v;
                    }
                }
            }
        }
        if (nxt) __syncthreads();         // Ts ready for next iter
    }
}

// ---------- fused window attention + output projection (v6: half-window blocks) ----------
// 6 waves x 384 threads, 2 blocks per window (half = 32 tokens each). Each
// wave owns one head: scatters its own Vt (no cross-wave dependency -> first
// barrier eliminated; same-wave LDS ordering via lgkmcnt), computes QK/
// softmax/PV for its half's 2 tj tiles, then proj for 32 cols x 32 rows.
// Rationale: v5's 12-wave blocks capped residency at 2 blocks/CU = 24/32
// waves (59% measured); 6-wave blocks allow 4-5 blocks/CU (75-94%).
// XCD swizzle pairs a window's two half-blocks on one XCD so the doubled
// V read hits L2. NOTE (R19/R21): do NOT graft other bodies here.
__global__ __launch_bounds__(384)
void attn_proj_k(const bf16* __restrict__ qkvw, const void* __restrict__ bias,
                 const bf16* __restrict__ pwT, const void* __restrict__ proj_b,
                 bf16* __restrict__ attnf, const int* __restrict__ flags) {
    __shared__ __align__(16) char SM[24576];   // Vt (per-head 4096 B) / cat alias (12288 B)

    const int fbias = flags[FBIAS];
    const int wid = threadIdx.x >> 6, lane = threadIdx.x & 63;
    const int h = wid;                         // one wave per head
    // XCD swizzle: paired works (2w, 2w+1) come from bids 8 apart -> same XCD
    const int work = (blockIdx.x & 7) * 512 + (blockIdx.x >> 3);
    const int w = work >> 1, half = work & 1;
    const int l15 = lane & 15, quad = lane >> 4;
    bfr* vtp = (bfr*)(SM + h * 4096);          // [32][64] per head, swizzled cols

    const bfr* qb = (const bfr*)qkvw + ((long long)w * 6 + h) * 2048;           // sel 0
    const bfr* kb = qb + (long long)NWIN * 6 * 2048;                            // sel 1
    const bfr* vb = kb + (long long)NWIN * 6 * 2048;                            // sel 2

    // ---- phase 1a: V load + Vt scatter (every wave, own head) ----
    {
        const bfr* vp = vb + lane * 32;
        bf16x8 v0 = *(const bf16x8*)(vp);
        bf16x8 v1 = *(const bf16x8*)(vp + 8);
        bf16x8 v2 = *(const bf16x8*)(vp + 16);
        bf16x8 v3 = *(const bf16x8*)(vp + 24);
#pragma unroll
        for (int j = 0; j < 8; ++j) {
            int sc = lane ^ (j << 3);
            vtp[j * 64 + sc]        = v0[j];
            vtp[(j + 8) * 64 + sc]  = v1[j];
            vtp[(j + 16) * 64 + sc] = v2[j];
            vtp[(j + 24) * 64 + sc] = v3[j];
        }
    }

    // ---- phase 1b: K (all 4 tiles) + Q (this half's 2 tiles) ----
    bf16x8 bk[4], aq[2];
#pragma unroll
    for (int ti = 0; ti < 4; ++ti)
        bk[ti] = *(const bf16x8*)(kb + (ti * 16 + l15) * 32 + quad * 8);
#pragma unroll
    for (int tj2 = 0; tj2 < 2; ++tj2)
        aq[tj2] = *(const bf16x8*)(qb + ((half * 2 + tj2) * 16 + l15) * 32 + quad * 8);

    // ---- phase 2+3: QK + softmax + pack (register-only) ----
    const float scale = 0.17677669529663689f;   // 1/sqrt(32)
    const long long bias0 = (long long)h * 4096;
    unsigned Wreg[2][4][2];   // [tj2][ti][pair]
#pragma unroll
    for (int tj2 = 0; tj2 < 2; ++tj2) {
        const int tj = half * 2 + tj2;
        f32x4 T[4];
        __builtin_amdgcn_s_setprio(1);
#pragma unroll
        for (int ti = 0; ti < 4; ++ti) {
            f32x4 z = {0.f, 0.f, 0.f, 0.f};
            T[ti] = __builtin_amdgcn_mfma_f32_16x16x32_bf16(bk[ti], aq[tj2], z, 0, 0, 0);
        }
        __builtin_amdgcn_s_setprio(0);
        const long long brow = bias0 + (tj * 16 + l15) * 64 + quad * 4;
        float mloc = -3.0e38f;
#pragma unroll
        for (int ti = 0; ti < 4; ++ti) {
            f32x4 bv4 = ld4f(bias, brow + ti * 16, fbias);
#pragma unroll
            for (int r = 0; r < 4; ++r) {
                float v = T[ti][r] * scale + bv4[r];
                T[ti][r] = v;
                mloc = fmaxf(mloc, v);
            }
        }
        mloc = fmaxf(mloc, __shfl_xor(mloc, 16));
        mloc = fmaxf(mloc, __shfl_xor(mloc, 32));
        float l = 0.f;
#pragma unroll
        for (int ti = 0; ti < 4; ++ti)
#pragma unroll
            for (int r = 0; r < 4; ++r) {
                float e = __expf(T[ti][r] - mloc);
                T[ti][r] = e;
                l += e;
            }
        l += __shfl_xor(l, 16);
        l += __shfl_xor(l, 32);
        float linv = 1.0f / l;
#pragma unroll
        for (int ti = 0; ti < 4; ++ti) {
            Wreg[tj2][ti][0] = pk2bf(T[ti][0] * linv, T[ti][1] * linv);
            Wreg[tj2][ti][1] = pk2bf(T[ti][2] * linv, T[ti][3] * linv);
        }
    }

    // (no barrier: Vt written and read by the SAME wave; lgkmcnt orders LDS)

    // ---- phase 4: O = P @ V; P-frags gathered in-register via shfl ----
    const int vsw = (l15 & 7) << 3;
    bf16x8 bv[2][2];
#pragma unroll
    for (int kc = 0; kc < 2; ++kc) {
        bv[kc][0] = *(const bf16x8*)&vtp[l15 * 64 + ((kc * 32 + quad * 8) ^ vsw)];
        bv[kc][1] = *(const bf16x8*)&vtp[(16 + l15) * 64 + ((kc * 32 + quad * 8) ^ vsw)];
    }
    const int hi = quad >> 1, qlow = quad & 1;
    f32x4 O[2][2];
#pragma unroll
    for (int tj2 = 0; tj2 < 2; ++tj2) {
        O[tj2][0] = f32x4{0.f, 0.f, 0.f, 0.f};
        O[tj2][1] = O[tj2][0];
    }
#pragma unroll
    for (int tj2 = 0; tj2 < 2; ++tj2)
#pragma unroll
        for (int kc = 0; kc < 2; ++kc) {
            union { unsigned u[4]; bf16x8 v; } ap;
#pragma unroll
            for (int j2 = 0; j2 < 4; ++j2) {
                int srcl = (2 * qlow + (j2 >> 1)) * 16 + l15;
                unsigned va = (unsigned)__shfl((int)Wreg[tj2][2 * kc][j2 & 1], srcl);
                unsigned vb2 = (unsigned)__shfl((int)Wreg[tj2][2 * kc + 1][j2 & 1], srcl);
                ap.u[j2] = hi ? vb2 : va;
            }
            __builtin_amdgcn_s_setprio(1);
            O[tj2][0] = __builtin_amdgcn_mfma_f32_16x16x32_bf16(ap.v, bv[kc][0], O[tj2][0], 0, 0, 0);
            O[tj2][1] = __builtin_amdgcn_mfma_f32_16x16x32_bf16(ap.v, bv[kc][1], O[tj2][1], 0, 0, 0);
            __builtin_amdgcn_s_setprio(0);
        }

    // ---- issue proj B-fragment + bias loads early (hide under cat phase) ----
    // wave wid owns 32 output cols = 2 groups of 16
    const int fpb = flags[FPROJB];
    float pbv[2];
    bf16x8 pw[2][6];
#pragma unroll
    for (int cg = 0; cg < 2; ++cg) {
        int pcol = wid * 32 + cg * 16 + l15;
        pbv[cg] = ldin(proj_b, pcol, fpb);
#pragma unroll
        for (int ks = 0; ks < 6; ++ks)
            pw[cg][ks] = *(const bf16x8*)((const bfr*)pwT + (long long)pcol * 192 + ks * 32 + quad * 8);
    }

    __syncthreads();   // all waves done with Vt; SM becomes cat (32 rows x 384 B)

    // ---- phase 5: assemble cat tile [32][384 B] (XOR-swizzled rows) ----
#pragma unroll
    for (int tj2 = 0; tj2 < 2; ++tj2)
#pragma unroll
        for (int n2 = 0; n2 < 2; ++n2)
#pragma unroll
            for (int r = 0; r < 4; ++r) {
                int row = tj2 * 16 + quad * 4 + r;     // local row (this half)
                int cb = (h * 64 + n2 * 32 + l15 * 2) ^ ((row & 7) << 4);
                *(bf16*)(SM + row * 384 + cb) = __float2bfloat16(O[tj2][n2][r]);
            }

    __syncthreads();   // cat complete

    // ---- phase 6: proj -- wave wid computes 32 cols over the half's 32 rows ----
    const int csw = (l15 & 7) << 4;
    f32x4 pacc[2][2];
#pragma unroll
    for (int cg = 0; cg < 2; ++cg) {
        pacc[cg][0] = f32x4{0.f, 0.f, 0.f, 0.f};
        pacc[cg][1] = pacc[cg][0];
    }
#pragma unroll
    for (int ks = 0; ks < 6; ++ks) {
#pragma unroll
        for (int mt = 0; mt < 2; ++mt) {
            bf16x8 af = *(const bf16x8*)(SM + (mt * 16 + l15) * 384 +
                                         ((ks * 64 + quad * 16) ^ csw));
            pacc[0][mt] = __builtin_amdgcn_mfma_f32_16x16x32_bf16(af, pw[0][ks], pacc[0][mt], 0, 0, 0);
            pacc[1][mt] = __builtin_amdgcn_mfma_f32_16x16x32_bf16(af, pw[1][ks], pacc[1][mt], 0, 0, 0);
        }
    }

    // ---- phase 7: bias + window-ordered store to attnf ----
#pragma unroll
    for (int cg = 0; cg < 2; ++cg) {
        int pcol = wid * 32 + cg * 16 + l15;
#pragma unroll
        for (int mt = 0; mt < 2; ++mt)
#pragma unroll
            for (int r = 0; r < 4; ++r) {
                long long row = (long long)w * 64 + half * 32 + mt * 16 + quad * 4 + r;
                attnf[row * CCH + pcol] = __float2bfloat16(pacc[cg][mt][r] + pbv[cg]);
            }
    }
}

// ---------- depthwise 3x3 conv, 4-pixel strip x 8 channels per thread ----------
// XCD-aware bijective block swizzle. POOL variant fuses the AIM pooled-sum.
template<bool GELU, int CX, bool POOL>
__global__ __launch_bounds__(256)
void dwconv_s4_k(const bf16* __restrict__ in, const float* __restrict__ wt,
                 bf16* __restrict__ out, float* __restrict__ pooled) {
    constexpr int CG = CX / 8;
    __shared__ float psum[POOL ? 192 : 1];
    if (POOL) {
        if (threadIdx.x < 192) psum[threadIdx.x] = 0.f;
        __syncthreads();
    }
    int cpx = gridDim.x >> 3;             // grid % 8 == 0
    int lb = (blockIdx.x & 7) * cpx + (blockIdx.x >> 3);
    long long idx = (long long)lb * 256 + threadIdx.x;
    int cg = (int)(idx % CG);
    long long s = idx / CG;               // strip id
    int xs = (int)(s & 31);
    long long by = s >> 5;                // b*128 + y
    int y = (int)(by & 127);
    int x0 = xs * 4;
    int c0 = cg * 8;
    const long long rowpix = by * 128;    // pixel index of row start (b*LTOK + y*128)

    float acc[4][8] = {};
#pragma unroll
    for (int dy = -1; dy <= 1; ++dy) {
        int yy = y + dy;
        if (yy < 0 || yy > 127) continue;
        const bf16* rp = in + ((rowpix + dy * 128) + x0) * CX + c0;
        float fcol[6][8];
#pragma unroll
        for (int ci = 0; ci < 6; ++ci) {
            int xx = x0 + ci - 1;
            if (xx < 0 || xx > 127) {
#pragma unroll
                for (int j = 0; j < 8; ++j) fcol[ci][j] = 0.f;
            } else {
                u16x8 v = *(const u16x8*)(rp + (ci - 1) * CX);
#pragma unroll
                for (int j = 0; j < 8; ++j) fcol[ci][j] = bfcvt(v[j]);
            }
        }
        const float* wb = wt + (dy + 1) * 3 * CX + c0;
#pragma unroll
        for (int dx = 0; dx < 3; ++dx) {
            f32x4 w0 = *(const f32x4*)(wb + dx * CX);
            f32x4 w1 = *(const f32x4*)(wb + dx * CX + 4);
#pragma unroll
            for (int px = 0; px < 4; ++px) {
#pragma unroll
                for (int j = 0; j < 4; ++j) {
                    acc[px][j]     += fcol[px + dx][j]     * w0[j];
                    acc[px][j + 4] += fcol[px + dx][j + 4] * w1[j];
                }
            }
        }
    }
    float sums[8] = {0.f, 0.f, 0.f, 0.f, 0.f, 0.f, 0.f, 0.f};
#pragma unroll
    for (int px = 0; px < 4; ++px) {
        __attribute__((aligned(16))) unsigned short ob[8];
#pragma unroll
        for (int j = 0; j < 8; ++j) {
            float vv = acc[px][j];
            if (GELU) vv = gelu_f(vv);
            if (POOL) sums[j] += vv;
            union { bf16 h; unsigned short u; } cv;
            cv.h = __float2bfloat16(vv);
            ob[j] = cv.u;
        }
        *(u16x8*)(out + (rowpix + x0 + px) * CX + c0) = *(const u16x8*)ob;
    }
    if (POOL) {
#pragma unroll
        for (int j = 0; j < 8; ++j)
            atomicAdd(&psum[c0 + j], sums[j]);
        __syncthreads();
        if (threadIdx.x < 192) {
            int b = (int)(by >> 7);       // uniform within block
            atomicAdd(&pooled[b * CCH + threadIdx.x], psum[threadIdx.x]);
        }
    }
}

// ---------- channel gate: cm = sigmoid(gelu(pooled@cg1^T)@cg2^T) ----------
__global__ void cm_k(const float* __restrict__ pooled, const void* __restrict__ w1,
                     const void* __restrict__ w2, float* __restrict__ cm,
                     const int* flags) {
    __shared__ float ps[192], g[24];
    int f1 = flags[FCG1], f2 = flags[FCG2];
    int b = blockIdx.x, c = threadIdx.x; // blockDim 192
    ps[c] = pooled[b * CCH + c] * (1.0f / 16384.0f);
    __syncthreads();
    if (c < 24) {
        float t = 0.f;
        for (int k = 0; k < 192; ++k) t += ps[k] * ldin(w1, c * 192 + k, f1);
        g[c] = gelu_f(t);
    }
    __syncthreads();
    float s = 0.f;
#pragma unroll
    for (int r = 0; r < 24; ++r) s += g[r] * ldin(w2, c * 24 + r, f2);
    cm[b * CCH + c] = 1.0f / (1.0f + expf(-s));
}

// ---------- x2 = x + attn*cm + conv (f32x4 vectorized, 16 lanes/token) ----------
__global__ __launch_bounds__(256)
void x2ln2_k(const void* __restrict__ x, const bf16* __restrict__ attnf,
             const bf16* __restrict__ conv, const float* __restrict__ cm,
             const void* __restrict__ w, const void* __restrict__ bb,
             float* __restrict__ x2, bf16* __restrict__ n2, const int* flags) {
    int fx = flags[FX], fw = flags[FN2W], fb = flags[FN2B];
    int wv = threadIdx.x >> 6, lane = threadIdx.x & 63;
    int gw = lane >> 4, l16 = lane & 15;
    long long t = (long long)blockIdx.x * 16 + wv * 4 + gw;
    int b = (int)(t >> 14);
    int l = (int)(t & 16383);
    int y = l >> 7, xx = l & 127;
    long long wrow = ((long long)b * 256 + (y >> 3) * 16 + (xx >> 3)) * 64 + (y & 7) * 8 + (xx & 7);

    f32x4 sv[3];
#pragma unroll
    for (int k = 0; k < 3; ++k) {
        int c0 = l16 * 4 + 64 * k;
        f32x4 xv  = ld4f(x, t * CCH + c0, fx);
        f32x4 af  = ld4b(attnf, wrow * CCH + c0);
        f32x4 cf  = ld4b(conv, t * CCH + c0);
        f32x4 cmv = *(const f32x4*)(cm + b * CCH + c0);
        f32x4 o;
#pragma unroll
        for (int j = 0; j < 4; ++j)
            o[j] = xv[j] + af[j] * cmv[j] + cf[j];
        *(f32x4*)(x2 + t * CCH + c0) = o;
        sv[k] = o;
    }
    float s = 0.f;
#pragma unroll
    for (int k = 0; k < 3; ++k) s += sv[k][0] + sv[k][1] + sv[k][2] + sv[k][3];
    s += __shfl_xor(s, 1); s += __shfl_xor(s, 2);
    s += __shfl_xor(s, 4); s += __shfl_xor(s, 8);
    float mean = s * (1.0f / 192.0f);
    float vs = 0.f;
#pragma unroll
    for (int k = 0; k < 3; ++k)
#pragma unroll
        for (int j = 0; j < 4; ++j) {
            float d = sv[k][j] - mean;
            vs += d * d;
        }
    vs += __shfl_xor(vs, 1); vs += __shfl_xor(vs, 2);
    vs += __shfl_xor(vs, 4); vs += __shfl_xor(vs, 8);
    float rstd = rsqrtf(vs * (1.0f / 192.0f) + 1e-5f);
#pragma unroll
    for (int k = 0; k < 3; ++k) {
        int c0 = l16 * 4 + 64 * k;
        f32x4 wv4 = ld4f(w, c0, fw);
        f32x4 bv4 = ld4f(bb, c0, fb);
        f32x4 o;
#pragma unroll
        for (int j = 0; j < 4; ++j)
            o[j] = (sv[k][j] - mean) * rstd * wv4[j] + bv4[j];
        st4b(n2, t * CCH + c0, o);
    }
}

// ---------- launch ----------
extern "C" void kernel_launch(void* const* d_in, const int* in_sizes, int n_in,
                              void* d_out, int out_size, void* d_ws, size_t ws_size,
                              hipStream_t stream) {
    (void)n_in; (void)out_size; (void)ws_size;
    float* out = (float*)d_out;

    char* wsp = (char*)d_ws;
    size_t off = 0;
    auto alloc = [&](size_t bytes) -> char* {
        char* p = wsp + off;
        off += (bytes + 255) & ~(size_t)255;
        return p;
    };
    int*  flags   = (int*)alloc(15 * 4);
    bf16* qkv_wT  = (bf16*)alloc(576 * 192 * 2);
    bf16* proj_wT = (bf16*)alloc(192 * 192 * 2);
    bf16* fc1_wT  = (bf16*)alloc(384 * 192 * 2);
    bf16* fc2_wT  = (bf16*)alloc(192 * 384 * 2);
    float* convwT = (float*)alloc(9 * CCH * 4);      // tap-major dw-conv weights
    float* smixwT = (float*)alloc(9 * 384 * 4);
    float* pooled = (float*)alloc(BATCH * CCH * 4);
    float* cm     = (float*)alloc(BATCH * CCH * 4);
    char* Rbig    = alloc(BL * 576 * 2);          // 150,994,944 B
    char* Rpair   = alloc(BL * 384 * 2);          // 100,663,296 B

    // Buffer lifetimes (R18-verified layout):
    //  qkvb  = Rbig [3][NWIN][6][64][32]  dead after attn_proj
    //  convf = Rbig front [BL,192]        written after qkvb dead; dead after x2ln2
    //  hbuf  = Rbig front [BL,384]        written by fc1 after convf dead
    //  n1/n2 = Rpair front [BL,192]
    //  attnf = Rpair tail  [BL,192]       dead after x2ln2
    //  h2    = Rpair [BL,384]             written by dwconv384 after n2+attnf dead
    bf16* qkvb  = (bf16*)Rbig;
    bf16* convf = (bf16*)Rbig;
    bf16* hbuf  = (bf16*)Rbig;
    bf16* n1    = (bf16*)Rpair;
    bf16* attnf = (bf16*)(Rpair + (size_t)BL * 192 * 2);
    bf16* n2    = n1;
    bf16* h2    = (bf16*)Rpair;
    float* x2   = out;                                       // x2 lives in d_out (f32)

    const int imap[15] = {0, 3, 4, 5, 6, 7, 8, 9, 10, 11, 12, 13, 14, 15, 16};
    InPtrs ip;
    for (int i = 0; i < 15; ++i) { ip.p[i] = d_in[imap[i]]; ip.n[i] = in_sizes[imap[i]]; }
    const void* x        = d_in[0];
    const void* proj_b   = d_in[7];
    const void* attnbias = d_in[8];
    const void* cg_w1    = d_in[10];
    const void* cg_w2    = d_in[11];

    // fused prologue: probe + all weight transposes + pooled zero (1 dispatch)
    prep_k<<<1194, 256, 0, stream>>>(ip, flags, qkv_wT, proj_wT, fc1_wT, fc2_wT,
                                     convwT, smixwT, pooled);

    // LN1
    ln_kernel<<<BL / 16, 256, 0, stream>>>(x, d_in[3], d_in[4], n1, flags);
    // qkv = n1 @ qkv_w, window-aligned M-tiles -> window/head-major layout
    gemm2_k<0, 192, 576, bf16><<<BL / 64, 256, 0, stream>>>(n1, qkv_wT, qkvb, nullptr, nullptr, flags);
    // fused window attention + proj -> attnf (two 384-thread blocks per window)
    attn_proj_k<<<NWIN * 2, 384, 0, stream>>>(qkvb, attnbias, proj_wT, proj_b, attnf, flags);
    // conv branch: conv_feat = gelu(dwconv(n1)) -> Rbig front (qkvb dead);
    // fused AIM pooled-sum (replaces pool_k)
    dwconv_s4_k<true, 192, true><<<(int)(BL / 4 * 24 / 256), 256, 0, stream>>>(n1, convwT, convf, pooled);
    // channel gate (tiny dedicated dispatch; in-block recompute cost 150 us, R17)
    cm_k<<<BATCH, 192, 0, stream>>>(pooled, cg_w1, cg_w2, cm, flags);
    // x2 (f32 -> d_out) + LN2 (n2 overwrites n1)
    x2ln2_k<<<BL / 16, 256, 0, stream>>>(x, attnf, convf, cm, d_in[12], d_in[13], x2, n2, flags);
    // FFN: h = gelu(n2 @ fc1_w) -> Rbig (convf dead)
    gemm2_k<2, 192, 384, bf16><<<BL / 64, 256, 0, stream>>>(n2, fc1_wT, hbuf, nullptr, nullptr, flags);
    // spatial mix dwconv -> h2 (overwrites n2+attnf, both dead)
    dwconv_s4_k<false, 384, false><<<(int)(BL / 4 * 48 / 256), 256, 0, stream>>>(hbuf, smixwT, h2, nullptr);
    // out = x2 + h2 @ fc2_w   (in-place f32 RMW on d_out)
    gemm2_k<3, 384, 192, float><<<BL / 64, 256, 0, stream>>>(h2, fc2_wT, out, nullptr, x2, flags);
}

// Round 25
// 587.020 us; speedup vs baseline: 1.0188x; 1.0188x over previous
//
#include <hip/hip_runtime.h>
#include <hip/hip_bf16.h>
#include <math.h>

// ---------- constants (fixed problem shape) ----------
#define BATCH 8
#define CCH 192
#define LTOK 16384            // 128*128
#define BL 131072LL           // BATCH * LTOK
#define NWIN 2048             // BATCH * 16 * 16
#define NHEADS 6

typedef __hip_bfloat16 bf16;
typedef __bf16 bfr;  // raw bf16 for MFMA fragments
typedef bfr bf16x8 __attribute__((ext_vector_type(8)));
typedef float f32x4 __attribute__((ext_vector_type(4)));
typedef unsigned short u16x8 __attribute__((ext_vector_type(8)));
typedef unsigned short u16x4 __attribute__((ext_vector_type(4)));
typedef unsigned int u32x2 __attribute__((ext_vector_type(2)));

// ---------- dtype flags (1 = f32, 0 = bf16), probed at runtime ----------
#define FX     0
#define FN1W   1
#define FN1B   2
#define FQKVW  3
#define FPROJW 4
#define FPROJB 5
#define FBIAS  6
#define FCONVW 7
#define FCG1   8
#define FCG2   9
#define FN2W   10
#define FN2B   11
#define FFC1   12
#define FSMIX  13
#define FFC2   14

struct InPtrs { const void* p[15]; int n[15]; };

__device__ __forceinline__ float ldin(const void* p, long long i, int f32) {
    return f32 ? ((const float*)p)[i]
               : __bfloat162float(((const bf16*)p)[i]);
}

__device__ __forceinline__ float bfcvt(unsigned short u) {
    return __uint_as_float((unsigned)u << 16);
}

// 4 consecutive elements, dtype-flag dispatch (flag is wave-uniform)
__device__ __forceinline__ f32x4 ld4f(const void* p, long long i, int f32) {
    if (f32) return *(const f32x4*)((const float*)p + i);
    u16x4 v = *(const u16x4*)((const bf16*)p + i);
    f32x4 r;
    r[0] = bfcvt(v[0]); r[1] = bfcvt(v[1]); r[2] = bfcvt(v[2]); r[3] = bfcvt(v[3]);
    return r;
}
__device__ __forceinline__ f32x4 ld4b(const bf16* p, long long i) {
    u16x4 v = *(const u16x4*)(p + i);
    f32x4 r;
    r[0] = bfcvt(v[0]); r[1] = bfcvt(v[1]); r[2] = bfcvt(v[2]); r[3] = bfcvt(v[3]);
    return r;
}
__device__ __forceinline__ void st4b(bf16* p, long long i, f32x4 v) {
    union { bf16 h; unsigned short u; } cv;
    u16x4 o;
    cv.h = __float2bfloat16(v[0]); o[0] = cv.u;
    cv.h = __float2bfloat16(v[1]); o[1] = cv.u;
    cv.h = __float2bfloat16(v[2]); o[2] = cv.u;
    cv.h = __float2bfloat16(v[3]); o[3] = cv.u;
    *(u16x4*)(p + i) = o;
}

// pack two f32 -> one u32 of two bf16 (lo = a, hi = b)
__device__ __forceinline__ unsigned pk2bf(float a, float b) {
    union { bf16 h; unsigned short u; } ca, cb;
    ca.h = __float2bfloat16(a);
    cb.h = __float2bfloat16(b);
    return (unsigned)ca.u | ((unsigned)cb.u << 16);
}

__device__ __forceinline__ float gelu_f(float v) {
    return 0.5f * v * (1.0f + erff(v * 0.70710678118654752f));
}

// ---------- local dtype probe (block-level, re-run per consumer block) ----------
__device__ int local_probe(const void* p_, int n) {
    __shared__ int sh0, sh1, sh2;
    if (threadIdx.x == 0) { sh0 = 0; sh1 = 0; sh2 = 0; }
    __syncthreads();
    const bf16* p = (const bf16*)p_;
    int m = n < 2048 ? n : 2048;
    bool insane = false, evennz = false, oddnz = false;
    for (int i = threadIdx.x; i < m; i += 256) {
        float v = __bfloat162float(p[i]);
        if (!(fabsf(v) <= 1e9f)) insane = true;   // NaN/inf/huge
        if (v != 0.0f) { if (i & 1) oddnz = true; else evennz = true; }
    }
    if (insane) sh0 = 1;
    if (evennz) sh1 = 1;
    if (oddnz)  sh2 = 1;
    __syncthreads();
    return (sh0 || (!sh1 && sh2)) ? 1 : 0;
}

// ---------- fused prologue: probe + transposes + pooled zero, one dispatch ----------
__global__ __launch_bounds__(256)
void prep_k(InPtrs ip, int* __restrict__ flags,
            bf16* __restrict__ qkv_wT, bf16* __restrict__ proj_wT,
            bf16* __restrict__ fc1_wT, bf16* __restrict__ fc2_wT,
            float* __restrict__ convwT, float* __restrict__ smixwT,
            float* __restrict__ pooled) {
    int blk = blockIdx.x;
    // section 0: probe -> flags [15 blocks]
    if (blk < 15) {
        int f = local_probe(ip.p[blk], ip.n[blk]);
        if (threadIdx.x == 0) flags[blk] = f;
        return;
    }
    blk -= 15;
    // section 1: qkv_w [192,576] -> qkv_wT [576,192]  [432 blocks]
    if (blk < 432) {
        int f = local_probe(ip.p[FQKVW], ip.n[FQKVW]);
        int idx = blk * 256 + threadIdx.x;
        int k = idx / 576, n = idx - k * 576;
        qkv_wT[(long long)n * 192 + k] = __float2bfloat16(ldin(ip.p[FQKVW], idx, f));
        return;
    }
    blk -= 432;
    // section 2: proj_w [192,192] -> proj_wT [192,192]  [144 blocks]
    if (blk < 144) {
        int f = local_probe(ip.p[FPROJW], ip.n[FPROJW]);
        int idx = blk * 256 + threadIdx.x;
        int k = idx / 192, n = idx - k * 192;
        proj_wT[(long long)n * 192 + k] = __float2bfloat16(ldin(ip.p[FPROJW], idx, f));
        return;
    }
    blk -= 144;
    // section 3: fc1_w [192,384] -> fc1_wT [384,192]  [288 blocks]
    if (blk < 288) {
        int f = local_probe(ip.p[FFC1], ip.n[FFC1]);
        int idx = blk * 256 + threadIdx.x;
        int k = idx / 384, n = idx - k * 384;
        fc1_wT[(long long)n * 192 + k] = __float2bfloat16(ldin(ip.p[FFC1], idx, f));
        return;
    }
    blk -= 288;
    // section 4: fc2_w [384,192] -> fc2_wT [192,384]  [288 blocks]
    if (blk < 288) {
        int f = local_probe(ip.p[FFC2], ip.n[FFC2]);
        int idx = blk * 256 + threadIdx.x;
        int k = idx / 192, n = idx - k * 192;
        fc2_wT[(long long)n * 384 + k] = __float2bfloat16(ldin(ip.p[FFC2], idx, f));
        return;
    }
    blk -= 288;
    // section 5: conv_w [192,1,3,3] -> convwT [9][192]  [7 blocks]
    if (blk < 7) {
        int f = local_probe(ip.p[FCONVW], ip.n[FCONVW]);
        int idx = blk * 256 + threadIdx.x;
        if (idx < 192 * 9) {
            int c = idx / 9, t = idx - c * 9;
            convwT[t * 192 + c] = ldin(ip.p[FCONVW], idx, f);
        }
        return;
    }
    blk -= 7;
    // section 6: smix_w [384,1,3,3] -> smixwT [9][384]  [14 blocks]
    if (blk < 14) {
        int f = local_probe(ip.p[FSMIX], ip.n[FSMIX]);
        int idx = blk * 256 + threadIdx.x;
        if (idx < 384 * 9) {
            int c = idx / 9, t = idx - c * 9;
            smixwT[t * 384 + c] = ldin(ip.p[FSMIX], idx, f);
        }
        return;
    }
    blk -= 14;
    // section 7: zero pooled [6 blocks, 1536 floats]
    {
        int idx = blk * 256 + threadIdx.x;
        if (idx < BATCH * CCH) pooled[idx] = 0.f;
    }
}

// ---------- LayerNorm, 16 lanes per token, vectorized ----------
__global__ __launch_bounds__(256)
void ln_kernel(const void* __restrict__ x, const void* __restrict__ w,
               const void* __restrict__ b, bf16* __restrict__ out,
               const int* flags) {
    int fx = flags[FX], fw = flags[FN1W], fb = flags[FN1B];
    int wv = threadIdx.x >> 6, lane = threadIdx.x & 63;
    int gw = lane >> 4, l16 = lane & 15;
    long long t = (long long)blockIdx.x * 16 + wv * 4 + gw;
    long long base = t * CCH;
    f32x4 v[3];
#pragma unroll
    for (int k = 0; k < 3; ++k)
        v[k] = ld4f(x, base + l16 * 4 + 64 * k, fx);
    float s = 0.f;
#pragma unroll
    for (int k = 0; k < 3; ++k) s += v[k][0] + v[k][1] + v[k][2] + v[k][3];
    s += __shfl_xor(s, 1); s += __shfl_xor(s, 2);
    s += __shfl_xor(s, 4); s += __shfl_xor(s, 8);
    float mean = s * (1.0f / 192.0f);
    float vs = 0.f;
#pragma unroll
    for (int k = 0; k < 3; ++k)
#pragma unroll
        for (int j = 0; j < 4; ++j) {
            float d = v[k][j] - mean;
            vs += d * d;
        }
    vs += __shfl_xor(vs, 1); vs += __shfl_xor(vs, 2);
    vs += __shfl_xor(vs, 4); vs += __shfl_xor(vs, 8);
    float rstd = rsqrtf(vs * (1.0f / 192.0f) + 1e-5f);
#pragma unroll
    for (int k = 0; k < 3; ++k) {
        int c0 = l16 * 4 + 64 * k;
        f32x4 wv4 = ld4f(w, c0, fw);
        f32x4 bv4 = ld4f(b, c0, fb);
        f32x4 o;
#pragma unroll
        for (int j = 0; j < 4; ++j)
            o[j] = (v[k][j] - mean) * rstd * wv4[j] + bv4[j];
        st4b(out, base + c0, o);
    }
}

// ---------- LDS-staged MFMA GEMM (R8-verified single-buffer form) ----------
// EPI=0 (WINM): M-tiles window-aligned; C stores into window/head-major
// qkvw[sel][w][h][tin][32], all writes confined to one window's region.
template<int EPI, int KK, int NN, typename CT>
__global__ __launch_bounds__(256)
void gemm2_k(const bf16* __restrict__ A_, const bf16* __restrict__ BT_,
             CT* __restrict__ Cmat, const void* __restrict__ bias,
             const float* __restrict__ res, const int* __restrict__ flags) {
    constexpr int KT = KK / 192;          // k-tiles of 192
    constexpr int NC = NN / 64;           // n-chunks of 64
    constexpr int NITER = NC * KT;
    constexpr int GSTR = KK * 2;          // global row stride (bytes)
    constexpr bool WINM = (EPI == 0);
    __shared__ __align__(16) char Ts[64 * 384];   // shared A-prologue / B-tile buffer

    const int fb = (EPI == 1) ? flags[FPROJB] : 0;
    const int tid = threadIdx.x;
    const int lane = tid & 63, wv = tid >> 6;
    const int r16 = lane & 15, q = lane >> 4;
    const long long m0 = (long long)blockIdx.x * 64;
    const int swz = (r16 & 7) << 4;

    // window decomposition (WINM only)
    const int wdx = blockIdx.x;
    const int wb = wdx >> 8, wrem = wdx & 255, wy = wrem >> 4, wx = wrem & 15;
    const long long tokbase = (long long)wb * LTOK + (wy * 8) * 128 + wx * 8;

    f32x4 pre[6];
    auto loadB = [&](int itn) {
        int nc2 = itn / KT, kt2 = itn - nc2 * KT;
#pragma unroll
        for (int p = 0; p < 6; ++p) {
            int off = p * 4096 + tid * 16;
            int row = off / 384, col = off - row * 384;
            pre[p] = *(const f32x4*)((const char*)BT_ +
                     (long long)(nc2 * 64 + row) * GSTR + kt2 * 384 + col);
        }
    };
    auto writeT = [&]() {
#pragma unroll
        for (int p = 0; p < 6; ++p) {
            int off = p * 4096 + tid * 16;
            int row = off / 384, col = off - row * 384;
            *(f32x4*)(Ts + row * 384 + (col ^ ((row & 7) << 4))) = pre[p];
        }
    };

    loadB(0);                             // B(0) in flight during A prologue

    // ---- A prologue: per-k-tile stage through Ts, hoist fragments ----
    bf16x8 afrag[KK / 32];
    const char* Arow = Ts + (wv * 16 + r16) * 384;
    const char* asrc = (const char*)A_;
#pragma unroll
    for (int kt = 0; kt < KT; ++kt) {
#pragma unroll
        for (int p = 0; p < 6; ++p) {
            int off = p * 4096 + tid * 16;
            int row = off / 384, col = off - row * 384;
            long long grow = WINM ? (tokbase + (row >> 3) * 128 + (row & 7))
                                  : (m0 + row);
            *(f32x4*)(Ts + row * 384 + (col ^ ((row & 7) << 4))) =
                *(const f32x4*)(asrc + grow * GSTR + kt * 384 + col);
        }
        __syncthreads();
#pragma unroll
        for (int ks = 0; ks < 6; ++ks)
            afrag[kt * 6 + ks] = *(const bf16x8*)(Arow + ((ks * 64 + q * 16) ^ swz));
        __syncthreads();                  // readers done before buffer reuse
    }
    writeT();                             // B(0) -> Ts
    __syncthreads();

    f32x4 acc0, acc1, acc2, acc3;
    float resv[16];

    for (int it = 0; it < NITER; ++it) {
        const int nc = it / KT, kt = it - nc * KT;
        if (kt == 0) {
            acc0 = f32x4{0.f, 0.f, 0.f, 0.f};
            acc1 = acc0; acc2 = acc0; acc3 = acc0;
            if (EPI == 3) {               // prefetch residual ahead of epilogue
#pragma unroll
                for (int j = 0; j < 4; ++j)
#pragma unroll
                    for (int r = 0; r < 4; ++r)
                        resv[j * 4 + r] =
                            res[(m0 + wv * 16 + q * 4 + r) * NN + nc * 64 + j * 16 + r16];
            }
        }
        const bool nxt = (it + 1 < NITER);
        if (nxt) loadB(it + 1);           // issue next B-tile early
#pragma unroll
        for (int ks = 0; ks < 6; ++ks) {
            bf16x8 a = afrag[kt * 6 + ks];
            const char* bb = Ts + r16 * 384 + ((ks * 64 + q * 16) ^ swz);
            bf16x8 b0 = *(const bf16x8*)(bb);
            bf16x8 b1 = *(const bf16x8*)(bb + 16 * 384);
            bf16x8 b2 = *(const bf16x8*)(bb + 32 * 384);
            bf16x8 b3 = *(const bf16x8*)(bb + 48 * 384);
            acc0 = __builtin_amdgcn_mfma_f32_16x16x32_bf16(a, b0, acc0, 0, 0, 0);
            acc1 = __builtin_amdgcn_mfma_f32_16x16x32_bf16(a, b1, acc1, 0, 0, 0);
            acc2 = __builtin_amdgcn_mfma_f32_16x16x32_bf16(a, b2, acc2, 0, 0, 0);
            acc3 = __builtin_amdgcn_mfma_f32_16x16x32_bf16(a, b3, acc3, 0, 0, 0);
        }
        __syncthreads();                  // all waves done reading Ts
        if (nxt) writeT();
        if (kt == KT - 1) {
            f32x4 accs[4] = {acc0, acc1, acc2, acc3};
#pragma unroll
            for (int j = 0; j < 4; ++j) {
                int col = nc * 64 + j * 16 + r16;
#pragma unroll
                for (int r = 0; r < 4; ++r) {
                    float v = accs[j][r];
                    if (EPI == 1) v += ldin(bias, col, fb);
                    if (EPI == 2) v = gelu_f(v);
                    if (EPI == 3) v += resv[j * 4 + r];
                    if (WINM) {
                        int tin = wv * 16 + q * 4 + r;
                        int sel = col / 192, rem2 = col - sel * 192;
                        int hh = rem2 >> 5, d = rem2 & 31;
                        Cmat[((((long long)sel * NWIN + wdx) * 6 + hh) * 64 + tin) * 32 + d] = (CT)v;
                    } else {
                        long long row = m0 + wv * 16 + q * 4 + r;
                        Cmat[row * NN + col] = (CT)v;
                    }
                }
            }
        }
        if (nxt) __syncthreads();         // Ts ready for next iter
    }
}

// ---------- fused window attention + output projection (v5: 12 waves, FINAL) ----------
// 2 waves per head, each owning 2 of the 4 tj row-tiles (Occupancy ~59%).
// Session lessons encoded here:
//  - R19/R21: do NOT graft other bodies in (VGPR alloc = max over paths/phases).
//  - R23: T5 setprio = null on this structure (removed; zero value measured).
//  - R24: do NOT split into half-window blocks -- Vt (all 6 heads' full V)
//    cannot split, so LDS/window doubles and occupancy DROPS (59->40%).
__global__ __launch_bounds__(768)
void attn_proj_k(const bf16* __restrict__ qkvw, const void* __restrict__ bias,
                 const bf16* __restrict__ pwT, const void* __restrict__ proj_b,
                 bf16* __restrict__ attnf, const int* __restrict__ flags) {
    __shared__ __align__(16) char SM[24576];   // Vt (per-head 4096 B) / cat alias

    const int fbias = flags[FBIAS];
    const int wid = threadIdx.x >> 6, lane = threadIdx.x & 63;
    const int h = wid >> 1, half = wid & 1;
    const int w = blockIdx.x;
    const int l15 = lane & 15, quad = lane >> 4;
    bfr* vtp = (bfr*)(SM + h * 4096);          // [32][64] per head, swizzled cols

    const bfr* qb = (const bfr*)qkvw + ((long long)w * 6 + h) * 2048;           // sel 0
    const bfr* kb = qb + (long long)NWIN * 6 * 2048;                            // sel 1
    const bfr* vb = kb + (long long)NWIN * 6 * 2048;                            // sel 2

    // ---- phase 1a: V load + Vt scatter (half-0 wave only) ----
    if (half == 0) {
        const bfr* vp = vb + lane * 32;
        bf16x8 v0 = *(const bf16x8*)(vp);
        bf16x8 v1 = *(const bf16x8*)(vp + 8);
        bf16x8 v2 = *(const bf16x8*)(vp + 16);
        bf16x8 v3 = *(const bf16x8*)(vp + 24);
#pragma unroll
        for (int j = 0; j < 8; ++j) {
            int sc = lane ^ (j << 3);
            vtp[j * 64 + sc]        = v0[j];
            vtp[(j + 8) * 64 + sc]  = v1[j];
            vtp[(j + 16) * 64 + sc] = v2[j];
            vtp[(j + 24) * 64 + sc] = v3[j];
        }
    }

    // ---- phase 1b: K (all 4 tiles) + Q (this wave's 2 tiles) ----
    bf16x8 bk[4], aq[2];
#pragma unroll
    for (int ti = 0; ti < 4; ++ti)
        bk[ti] = *(const bf16x8*)(kb + (ti * 16 + l15) * 32 + quad * 8);
#pragma unroll
    for (int tj2 = 0; tj2 < 2; ++tj2)
        aq[tj2] = *(const bf16x8*)(qb + ((half * 2 + tj2) * 16 + l15) * 32 + quad * 8);

    // ---- phase 2+3: QK + softmax + pack (register-only) ----
    const float scale = 0.17677669529663689f;   // 1/sqrt(32)
    const long long bias0 = (long long)h * 4096;
    unsigned Wreg[2][4][2];   // [tj2][ti][pair]
#pragma unroll
    for (int tj2 = 0; tj2 < 2; ++tj2) {
        const int tj = half * 2 + tj2;
        f32x4 T[4];
#pragma unroll
        for (int ti = 0; ti < 4; ++ti) {
            f32x4 z = {0.f, 0.f, 0.f, 0.f};
            T[ti] = __builtin_amdgcn_mfma_f32_16x16x32_bf16(bk[ti], aq[tj2], z, 0, 0, 0);
        }
        const long long brow = bias0 + (tj * 16 + l15) * 64 + quad * 4;
        float mloc = -3.0e38f;
#pragma unroll
        for (int ti = 0; ti < 4; ++ti) {
            f32x4 bv4 = ld4f(bias, brow + ti * 16, fbias);
#pragma unroll
            for (int r = 0; r < 4; ++r) {
                float v = T[ti][r] * scale + bv4[r];
                T[ti][r] = v;
                mloc = fmaxf(mloc, v);
            }
        }
        mloc = fmaxf(mloc, __shfl_xor(mloc, 16));
        mloc = fmaxf(mloc, __shfl_xor(mloc, 32));
        float l = 0.f;
#pragma unroll
        for (int ti = 0; ti < 4; ++ti)
#pragma unroll
            for (int r = 0; r < 4; ++r) {
                float e = __expf(T[ti][r] - mloc);
                T[ti][r] = e;
                l += e;
            }
        l += __shfl_xor(l, 16);
        l += __shfl_xor(l, 32);
        float linv = 1.0f / l;
#pragma unroll
        for (int ti = 0; ti < 4; ++ti) {
            Wreg[tj2][ti][0] = pk2bf(T[ti][0] * linv, T[ti][1] * linv);
            Wreg[tj2][ti][1] = pk2bf(T[ti][2] * linv, T[ti][3] * linv);
        }
    }

    __syncthreads();   // Vt scatter (half-0) visible to both waves

    // ---- phase 4: O = P @ V; P-frags gathered in-register via shfl ----
    const int vsw = (l15 & 7) << 3;
    bf16x8 bv[2][2];
#pragma unroll
    for (int kc = 0; kc < 2; ++kc) {
        bv[kc][0] = *(const bf16x8*)&vtp[l15 * 64 + ((kc * 32 + quad * 8) ^ vsw)];
        bv[kc][1] = *(const bf16x8*)&vtp[(16 + l15) * 64 + ((kc * 32 + quad * 8) ^ vsw)];
    }
    const int hi = quad >> 1, qlow = quad & 1;
    f32x4 O[2][2];
#pragma unroll
    for (int tj2 = 0; tj2 < 2; ++tj2) {
        O[tj2][0] = f32x4{0.f, 0.f, 0.f, 0.f};
        O[tj2][1] = O[tj2][0];
    }
#pragma unroll
    for (int tj2 = 0; tj2 < 2; ++tj2)
#pragma unroll
        for (int kc = 0; kc < 2; ++kc) {
            union { unsigned u[4]; bf16x8 v; } ap;
#pragma unroll
            for (int j2 = 0; j2 < 4; ++j2) {
                int srcl = (2 * qlow + (j2 >> 1)) * 16 + l15;
                unsigned va = (unsigned)__shfl((int)Wreg[tj2][2 * kc][j2 & 1], srcl);
                unsigned vb2 = (unsigned)__shfl((int)Wreg[tj2][2 * kc + 1][j2 & 1], srcl);
                ap.u[j2] = hi ? vb2 : va;
            }
            O[tj2][0] = __builtin_amdgcn_mfma_f32_16x16x32_bf16(ap.v, bv[kc][0], O[tj2][0], 0, 0, 0);
            O[tj2][1] = __builtin_amdgcn_mfma_f32_16x16x32_bf16(ap.v, bv[kc][1], O[tj2][1], 0, 0, 0);
        }

    // ---- issue proj B-fragment + bias loads early (hide under cat phase) ----
    const int fpb = flags[FPROJB];
    const int pcol = wid * 16 + l15;      // this wave's 16 output cols
    float pbv = ldin(proj_b, pcol, fpb);
    bf16x8 pw[6];
#pragma unroll
    for (int ks = 0; ks < 6; ++ks)
        pw[ks] = *(const bf16x8*)((const bfr*)pwT + (long long)pcol * 192 + ks * 32 + quad * 8);

    __syncthreads();   // all waves done with Vt; SM becomes cat

    // ---- phase 5: assemble cat tile [64][384 B] (XOR-swizzled rows) ----
#pragma unroll
    for (int tj2 = 0; tj2 < 2; ++tj2)
#pragma unroll
        for (int n2 = 0; n2 < 2; ++n2)
#pragma unroll
            for (int r = 0; r < 4; ++r) {
                int row = (half * 2 + tj2) * 16 + quad * 4 + r;
                int cb = (h * 64 + n2 * 32 + l15 * 2) ^ ((row & 7) << 4);
                *(bf16*)(SM + row * 384 + cb) = __float2bfloat16(O[tj2][n2][r]);
            }

    __syncthreads();   // cat complete

    // ---- phase 6: proj -- wave wid computes output cols [wid*16, wid*16+16) ----
    const int csw = (l15 & 7) << 4;
    f32x4 pacc[4];
#pragma unroll
    for (int mt = 0; mt < 4; ++mt)
        pacc[mt] = f32x4{0.f, 0.f, 0.f, 0.f};
#pragma unroll
    for (int ks = 0; ks < 6; ++ks) {
#pragma unroll
        for (int mt = 0; mt < 4; ++mt) {
            bf16x8 af = *(const bf16x8*)(SM + (mt * 16 + l15) * 384 +
                                         ((ks * 64 + quad * 16) ^ csw));
            pacc[mt] = __builtin_amdgcn_mfma_f32_16x16x32_bf16(af, pw[ks], pacc[mt], 0, 0, 0);
        }
    }

    // ---- phase 7: bias + window-ordered store to attnf ----
#pragma unroll
    for (int mt = 0; mt < 4; ++mt)
#pragma unroll
        for (int r = 0; r < 4; ++r) {
            long long row = (long long)w * 64 + mt * 16 + quad * 4 + r;
            attnf[row * CCH + pcol] = __float2bfloat16(pacc[mt][r] + pbv);
        }
}

// ---------- depthwise 3x3 conv, 4-pixel strip x 8 channels per thread ----------
// XCD-aware bijective block swizzle. POOL variant fuses the AIM pooled-sum.
template<bool GELU, int CX, bool POOL>
__global__ __launch_bounds__(256)
void dwconv_s4_k(const bf16* __restrict__ in, const float* __restrict__ wt,
                 bf16* __restrict__ out, float* __restrict__ pooled) {
    constexpr int CG = CX / 8;
    __shared__ float psum[POOL ? 192 : 1];
    if (POOL) {
        if (threadIdx.x < 192) psum[threadIdx.x] = 0.f;
        __syncthreads();
    }
    int cpx = gridDim.x >> 3;             // grid % 8 == 0
    int lb = (blockIdx.x & 7) * cpx + (blockIdx.x >> 3);
    long long idx = (long long)lb * 256 + threadIdx.x;
    int cg = (int)(idx % CG);
    long long s = idx / CG;               // strip id
    int xs = (int)(s & 31);
    long long by = s >> 5;                // b*128 + y
    int y = (int)(by & 127);
    int x0 = xs * 4;
    int c0 = cg * 8;
    const long long rowpix = by * 128;    // pixel index of row start (b*LTOK + y*128)

    float acc[4][8] = {};
#pragma unroll
    for (int dy = -1; dy <= 1; ++dy) {
        int yy = y + dy;
        if (yy < 0 || yy > 127) continue;
        const bf16* rp = in + ((rowpix + dy * 128) + x0) * CX + c0;
        float fcol[6][8];
#pragma unroll
        for (int ci = 0; ci < 6; ++ci) {
            int xx = x0 + ci - 1;
            if (xx < 0 || xx > 127) {
#pragma unroll
                for (int j = 0; j < 8; ++j) fcol[ci][j] = 0.f;
            } else {
                u16x8 v = *(const u16x8*)(rp + (ci - 1) * CX);
#pragma unroll
                for (int j = 0; j < 8; ++j) fcol[ci][j] = bfcvt(v[j]);
            }
        }
        const float* wb = wt + (dy + 1) * 3 * CX + c0;
#pragma unroll
        for (int dx = 0; dx < 3; ++dx) {
            f32x4 w0 = *(const f32x4*)(wb + dx * CX);
            f32x4 w1 = *(const f32x4*)(wb + dx * CX + 4);
#pragma unroll
            for (int px = 0; px < 4; ++px) {
#pragma unroll
                for (int j = 0; j < 4; ++j) {
                    acc[px][j]     += fcol[px + dx][j]     * w0[j];
                    acc[px][j + 4] += fcol[px + dx][j + 4] * w1[j];
                }
            }
        }
    }
    float sums[8] = {0.f, 0.f, 0.f, 0.f, 0.f, 0.f, 0.f, 0.f};
#pragma unroll
    for (int px = 0; px < 4; ++px) {
        __attribute__((aligned(16))) unsigned short ob[8];
#pragma unroll
        for (int j = 0; j < 8; ++j) {
            float vv = acc[px][j];
            if (GELU) vv = gelu_f(vv);
            if (POOL) sums[j] += vv;
            union { bf16 h; unsigned short u; } cv;
            cv.h = __float2bfloat16(vv);
            ob[j] = cv.u;
        }
        *(u16x8*)(out + (rowpix + x0 + px) * CX + c0) = *(const u16x8*)ob;
    }
    if (POOL) {
#pragma unroll
        for (int j = 0; j < 8; ++j)
            atomicAdd(&psum[c0 + j], sums[j]);
        __syncthreads();
        if (threadIdx.x < 192) {
            int b = (int)(by >> 7);       // uniform within block
            atomicAdd(&pooled[b * CCH + threadIdx.x], psum[threadIdx.x]);
        }
    }
}

// ---------- channel gate: cm = sigmoid(gelu(pooled@cg1^T)@cg2^T) ----------
__global__ void cm_k(const float* __restrict__ pooled, const void* __restrict__ w1,
                     const void* __restrict__ w2, float* __restrict__ cm,
                     const int* flags) {
    __shared__ float ps[192], g[24];
    int f1 = flags[FCG1], f2 = flags[FCG2];
    int b = blockIdx.x, c = threadIdx.x; // blockDim 192
    ps[c] = pooled[b * CCH + c] * (1.0f / 16384.0f);
    __syncthreads();
    if (c < 24) {
        float t = 0.f;
        for (int k = 0; k < 192; ++k) t += ps[k] * ldin(w1, c * 192 + k, f1);
        g[c] = gelu_f(t);
    }
    __syncthreads();
    float s = 0.f;
#pragma unroll
    for (int r = 0; r < 24; ++r) s += g[r] * ldin(w2, c * 24 + r, f2);
    cm[b * CCH + c] = 1.0f / (1.0f + expf(-s));
}

// ---------- x2 = x + attn*cm + conv (f32x4 vectorized, 16 lanes/token) ----------
__global__ __launch_bounds__(256)
void x2ln2_k(const void* __restrict__ x, const bf16* __restrict__ attnf,
             const bf16* __restrict__ conv, const float* __restrict__ cm,
             const void* __restrict__ w, const void* __restrict__ bb,
             float* __restrict__ x2, bf16* __restrict__ n2, const int* flags) {
    int fx = flags[FX], fw = flags[FN2W], fb = flags[FN2B];
    int wv = threadIdx.x >> 6, lane = threadIdx.x & 63;
    int gw = lane >> 4, l16 = lane & 15;
    long long t = (long long)blockIdx.x * 16 + wv * 4 + gw;
    int b = (int)(t >> 14);
    int l = (int)(t & 16383);
    int y = l >> 7, xx = l & 127;
    long long wrow = ((long long)b * 256 + (y >> 3) * 16 + (xx >> 3)) * 64 + (y & 7) * 8 + (xx & 7);

    f32x4 sv[3];
#pragma unroll
    for (int k = 0; k < 3; ++k) {
        int c0 = l16 * 4 + 64 * k;
        f32x4 xv  = ld4f(x, t * CCH + c0, fx);
        f32x4 af  = ld4b(attnf, wrow * CCH + c0);
        f32x4 cf  = ld4b(conv, t * CCH + c0);
        f32x4 cmv = *(const f32x4*)(cm + b * CCH + c0);
        f32x4 o;
#pragma unroll
        for (int j = 0; j < 4; ++j)
            o[j] = xv[j] + af[j] * cmv[j] + cf[j];
        *(f32x4*)(x2 + t * CCH + c0) = o;
        sv[k] = o;
    }
    float s = 0.f;
#pragma unroll
    for (int k = 0; k < 3; ++k) s += sv[k][0] + sv[k][1] + sv[k][2] + sv[k][3];
    s += __shfl_xor(s, 1); s += __shfl_xor(s, 2);
    s += __shfl_xor(s, 4); s += __shfl_xor(s, 8);
    float mean = s * (1.0f / 192.0f);
    float vs = 0.f;
#pragma unroll
    for (int k = 0; k < 3; ++k)
#pragma unroll
        for (int j = 0; j < 4; ++j) {
            float d = sv[k][j] - mean;
            vs += d * d;
        }
    vs += __shfl_xor(vs, 1); vs += __shfl_xor(vs, 2);
    vs += __shfl_xor(vs, 4); vs += __shfl_xor(vs, 8);
    float rstd = rsqrtf(vs * (1.0f / 192.0f) + 1e-5f);
#pragma unroll
    for (int k = 0; k < 3; ++k) {
        int c0 = l16 * 4 + 64 * k;
        f32x4 wv4 = ld4f(w, c0, fw);
        f32x4 bv4 = ld4f(bb, c0, fb);
        f32x4 o;
#pragma unroll
        for (int j = 0; j < 4; ++j)
            o[j] = (sv[k][j] - mean) * rstd * wv4[j] + bv4[j];
        st4b(n2, t * CCH + c0, o);
    }
}

// ---------- launch ----------
extern "C" void kernel_launch(void* const* d_in, const int* in_sizes, int n_in,
                              void* d_out, int out_size, void* d_ws, size_t ws_size,
                              hipStream_t stream) {
    (void)n_in; (void)out_size; (void)ws_size;
    float* out = (float*)d_out;

    char* wsp = (char*)d_ws;
    size_t off = 0;
    auto alloc = [&](size_t bytes) -> char* {
        char* p = wsp + off;
        off += (bytes + 255) & ~(size_t)255;
        return p;
    };
    int*  flags   = (int*)alloc(15 * 4);
    bf16* qkv_wT  = (bf16*)alloc(576 * 192 * 2);
    bf16* proj_wT = (bf16*)alloc(192 * 192 * 2);
    bf16* fc1_wT  = (bf16*)alloc(384 * 192 * 2);
    bf16* fc2_wT  = (bf16*)alloc(192 * 384 * 2);
    float* convwT = (float*)alloc(9 * CCH * 4);      // tap-major dw-conv weights
    float* smixwT = (float*)alloc(9 * 384 * 4);
    float* pooled = (float*)alloc(BATCH * CCH * 4);
    float* cm     = (float*)alloc(BATCH * CCH * 4);
    char* Rbig    = alloc(BL * 576 * 2);          // 150,994,944 B
    char* Rpair   = alloc(BL * 384 * 2);          // 100,663,296 B

    // Buffer lifetimes (R18-verified layout):
    //  qkvb  = Rbig [3][NWIN][6][64][32]  dead after attn_proj
    //  convf = Rbig front [BL,192]        written after qkvb dead; dead after x2ln2
    //  hbuf  = Rbig front [BL,384]        written by fc1 after convf dead
    //  n1/n2 = Rpair front [BL,192]
    //  attnf = Rpair tail  [BL,192]       dead after x2ln2
    //  h2    = Rpair [BL,384]             written by dwconv384 after n2+attnf dead
    bf16* qkvb  = (bf16*)Rbig;
    bf16* convf = (bf16*)Rbig;
    bf16* hbuf  = (bf16*)Rbig;
    bf16* n1    = (bf16*)Rpair;
    bf16* attnf = (bf16*)(Rpair + (size_t)BL * 192 * 2);
    bf16* n2    = n1;
    bf16* h2    = (bf16*)Rpair;
    float* x2   = out;                                       // x2 lives in d_out (f32)

    const int imap[15] = {0, 3, 4, 5, 6, 7, 8, 9, 10, 11, 12, 13, 14, 15, 16};
    InPtrs ip;
    for (int i = 0; i < 15; ++i) { ip.p[i] = d_in[imap[i]]; ip.n[i] = in_sizes[imap[i]]; }
    const void* x        = d_in[0];
    const void* proj_b   = d_in[7];
    const void* attnbias = d_in[8];
    const void* cg_w1    = d_in[10];
    const void* cg_w2    = d_in[11];

    // fused prologue: probe + all weight transposes + pooled zero (1 dispatch)
    prep_k<<<1194, 256, 0, stream>>>(ip, flags, qkv_wT, proj_wT, fc1_wT, fc2_wT,
                                     convwT, smixwT, pooled);

    // LN1
    ln_kernel<<<BL / 16, 256, 0, stream>>>(x, d_in[3], d_in[4], n1, flags);
    // qkv = n1 @ qkv_w, window-aligned M-tiles -> window/head-major layout
    gemm2_k<0, 192, 576, bf16><<<BL / 64, 256, 0, stream>>>(n1, qkv_wT, qkvb, nullptr, nullptr, flags);
    // fused window attention + proj -> attnf (one block per window, 12 waves)
    attn_proj_k<<<NWIN, 768, 0, stream>>>(qkvb, attnbias, proj_wT, proj_b, attnf, flags);
    // conv branch: conv_feat = gelu(dwconv(n1)) -> Rbig front (qkvb dead);
    // fused AIM pooled-sum (replaces pool_k)
    dwconv_s4_k<true, 192, true><<<(int)(BL / 4 * 24 / 256), 256, 0, stream>>>(n1, convwT, convf, pooled);
    // channel gate (tiny dedicated dispatch; in-block recompute cost 150 us, R17)
    cm_k<<<BATCH, 192, 0, stream>>>(pooled, cg_w1, cg_w2, cm, flags);
    // x2 (f32 -> d_out) + LN2 (n2 overwrites n1)
    x2ln2_k<<<BL / 16, 256, 0, stream>>>(x, attnf, convf, cm, d_in[12], d_in[13], x2, n2, flags);
    // FFN: h = gelu(n2 @ fc1_w) -> Rbig (convf dead)
    gemm2_k<2, 192, 384, bf16><<<BL / 64, 256, 0, stream>>>(n2, fc1_wT, hbuf, nullptr, nullptr, flags);
    // spatial mix dwconv -> h2 (overwrites n2+attnf, both dead)
    dwconv_s4_k<false, 384, false><<<(int)(BL / 4 * 48 / 256), 256, 0, stream>>>(hbuf, smixwT, h2, nullptr);
    // out = x2 + h2 @ fc2_w   (in-place f32 RMW on d_out)
    gemm2_k<3, 384, 192, float><<<BL / 64, 256, 0, stream>>>(h2, fc2_wT, out, nullptr, x2, flags);
}